// Round 6
// baseline (432.598 us; speedup 1.0000x reference)
//
#include <hip/hip_runtime.h>
#include <hip/hip_bf16.h>
#include <cstddef>
#include <cstdint>

// ModulatedConv2d: B=8, I=O=256, H=W=128, K=3, PAD=1, SD=512.
// y[b,o,p] = leaky( dscaled[b,o] * sum_{kh,kw,i} w[o,i,t] * (x*s)[b,i,p'] )
// R5: conv restructured to 128o x 256pix blocks (64x128 wave tiles, MFMA-bound),
//     xpack rewritten coalesced+LDS-transpose, demod split, style parallelized.

#define IN_C 256
#define OUT_C 256
#define HW 16384
#define W_IMG 128
#define SDIM 512
#define SCALE_F 0.020833333333333332f  // 1/48
#define EPS_F 1e-8f
#define NEG_SLOPE 0.2f

#define XROWB 8320   // per (b,iblk,row): 130 slots * 32 i * 2B
#define WTILEB 8192  // per (tap,oblk,iblk): 128 o * 32 i * 2B

typedef short bf16x8 __attribute__((ext_vector_type(8)));
typedef float f32x4 __attribute__((ext_vector_type(4)));

__device__ __forceinline__ unsigned short f2bf(float f) {
  unsigned u = __builtin_bit_cast(unsigned, f);
  unsigned r = u + 0x7FFFu + ((u >> 16) & 1u);
  return (unsigned short)(r >> 16);
}

__device__ __forceinline__ void glds16(const void* g, void* l) {
  __builtin_amdgcn_global_load_lds(
      (const __attribute__((address_space(1))) unsigned int*)g,
      (__attribute__((address_space(3))) unsigned int*)l, 16, 0, 0);
}

// ---- kernel 1: s[b][i] = style[b] . mod_w[i] + mod_b[i] --------------------
// grid (8 b, 4 iq), 256 thr: 64 channels/block, 4 threads per channel.
__global__ void style_mod_kernel(const float* __restrict__ style,
                                 const float* __restrict__ mod_w,
                                 const float* __restrict__ mod_b,
                                 float* __restrict__ s_out) {
  const int b = blockIdx.x, iq = blockIdx.y;
  const int il = threadIdx.x >> 2, part = threadIdx.x & 3;
  const int i = iq * 64 + il;
  const float4* st4 = (const float4*)(style + (size_t)b * SDIM) + part * 32;
  const float4* mw4 = (const float4*)(mod_w + (size_t)i * SDIM) + part * 32;
  float a = 0.f;
#pragma unroll 8
  for (int j = 0; j < 32; ++j) {
    float4 s = st4[j], w = mw4[j];
    a += s.x * w.x + s.y * w.y + s.z * w.z + s.w * w.w;
  }
  a += __shfl_xor(a, 1);
  a += __shfl_xor(a, 2);
  if (part == 0) s_out[b * IN_C + i] = a + mod_b[i];
}

// ---- kernel 2a: wsq[o][i] = sum_k weight[o][i][k]^2 ------------------------
__global__ void wsq_kernel(const float* __restrict__ weight,
                           float* __restrict__ wsq) {
  const int o = blockIdx.x, i = threadIdx.x;
  const float* wp = weight + ((size_t)o * IN_C + i) * 9;
  float s = 0.f;
#pragma unroll
  for (int k = 0; k < 9; ++k) s += wp[k] * wp[k];
  wsq[o * IN_C + i] = s;
}

// ---- kernel 2b: dscaled[b][o] = SCALE * rsqrt(SCALE^2*T + eps) -------------
// grid 256 (o), 256 thr (i); all 8 batches reduced per block.
__global__ void demod_kernel(const float* __restrict__ wsq,
                             const float* __restrict__ s_in,
                             float* __restrict__ dscaled) {
  const int o = blockIdx.x, i = threadIdx.x;
  const float wq = wsq[o * IN_C + i];
  float vb[8];
#pragma unroll
  for (int b = 0; b < 8; ++b) {
    float sv = s_in[b * IN_C + i];
    vb[b] = sv * sv * wq;
  }
#pragma unroll
  for (int b = 0; b < 8; ++b)
#pragma unroll
    for (int off = 32; off > 0; off >>= 1) vb[b] += __shfl_down(vb[b], off);
  __shared__ float red[4][8];
  const int lane = threadIdx.x & 63, wvid = threadIdx.x >> 6;
  if (lane == 0) {
#pragma unroll
    for (int b = 0; b < 8; ++b) red[wvid][b] = vb[b];
  }
  __syncthreads();
  if (threadIdx.x < 8) {
    float t = red[0][threadIdx.x] + red[1][threadIdx.x] +
              red[2][threadIdx.x] + red[3][threadIdx.x];
    dscaled[threadIdx.x * OUT_C + o] = SCALE_F * rsqrtf(SCALE_F * SCALE_F * t + EPS_F);
  }
}

// ---- kernel 3: pack W -> bf16 swizzled tiles [tap][oblk2][iblk8][128][32] --
__global__ void wpack_kernel(const float* __restrict__ weight,
                             unsigned char* __restrict__ wbf) {
  int tap = blockIdx.x, oblk = blockIdx.y, iblk = blockIdx.z;
  unsigned char* dst = wbf + ((size_t)((tap * 2 + oblk) * 8 + iblk)) * WTILEB;
  for (int t = threadIdx.x; t < 512; t += 256) {
    int oo = t >> 2, c = t & 3;
    int cp = c ^ ((oo >> 1) & 3);
    int o = oblk * 128 + oo;
    bf16x8 v;
#pragma unroll
    for (int j = 0; j < 8; ++j) {
      int i = iblk * 32 + c * 8 + j;
      v[j] = (short)f2bf(weight[((size_t)o * IN_C + i) * 9 + tap]);
    }
    *(bf16x8*)(dst + oo * 64 + cp * 16) = v;
  }
}

// ---- kernel 3b: zero the guard row used for vertical padding ---------------
__global__ void zfill_kernel(float4* __restrict__ zrow) {
  float4 z = {0.f, 0.f, 0.f, 0.f};
  for (int c = threadIdx.x; c < XROWB / 16; c += 256) zrow[c] = z;
}

// ---- kernel 4: pack X' = bf16(x*s), [b][iblk][row][130 slots][32 i] --------
// Coalesced float4 reads; LDS transpose (stride-33 pad); swizzled 16B stores.
__global__ __launch_bounds__(256) void xpack_kernel(
    const float* __restrict__ x, const float* __restrict__ s_in,
    unsigned char* __restrict__ xp) {
  __shared__ short xt[128 * 33];  // [pix][ch], +1 pad breaks conflicts
  const int tid = threadIdx.x;
  const int rb = blockIdx.x, iblk = blockIdx.y, b = blockIdx.z;
  const float* xbase = x + ((size_t)(b * IN_C + iblk * 32)) * HW;
  const int chp = tid >> 5;  // channel-in-pass
  const int lp = tid & 31;   // float4 index along row
  float sv[4];
#pragma unroll
  for (int p = 0; p < 4; ++p) sv[p] = s_in[b * IN_C + iblk * 32 + p * 8 + chp];

  for (int r = 0; r < 8; ++r) {
    const int row = rb * 8 + r;
#pragma unroll
    for (int p = 0; p < 4; ++p) {
      const int ch = p * 8 + chp;
      float4 v = *(const float4*)(xbase + (size_t)ch * HW + row * W_IMG + lp * 4);
      const int pix0 = lp * 4;
      xt[(pix0 + 0) * 33 + ch] = (short)f2bf(v.x * sv[p]);
      xt[(pix0 + 1) * 33 + ch] = (short)f2bf(v.y * sv[p]);
      xt[(pix0 + 2) * 33 + ch] = (short)f2bf(v.z * sv[p]);
      xt[(pix0 + 3) * 33 + ch] = (short)f2bf(v.w * sv[p]);
    }
    __syncthreads();
    unsigned char* dst = xp + ((size_t)((b * 8 + iblk) * 128 + row)) * XROWB;
    for (int task = tid; task < 520; task += 256) {
      int slot = task >> 2, c = task & 3;
      int cp = c ^ ((slot >> 1) & 3);
      int pix = slot - 1;
      bf16x8 v = (bf16x8)(short)0;
      if ((unsigned)pix < 128u) {
#pragma unroll
        for (int j = 0; j < 8; ++j) v[j] = xt[pix * 33 + c * 8 + j];
      }
      *(bf16x8*)(dst + slot * 64 + cp * 16) = v;
    }
    __syncthreads();
  }
}

// ---- kernel 5: conv GEMM ---------------------------------------------------
// grid (2 oblk, 64 hpair, 8 b); 256 thr = 4 waves (2 o-halves x 2 out-rows).
// Block tile: 128 o x 256 pix (2 rows). Wave tile 64 o x 128 pix (4x8 frags).
// Phase (i0, kh): stage 2 X rows (16.6KB) + 3 kw W tiles (24KB); compute
// 3 kw x (4 A-reads + 8 B-reads + 32 MFMA) per wave. LDS 41.2 KB.
__global__ __launch_bounds__(256, 2) void modconv_kernel(
    const unsigned char* __restrict__ xp, const unsigned char* __restrict__ wbf,
    const unsigned char* __restrict__ zrow, const float* __restrict__ dscaled,
    float* __restrict__ out) {
  __shared__ __align__(16) unsigned char lds[2 * XROWB + 3 * WTILEB];  // 41216B

  const int tid = threadIdx.x;
  const int lane = tid & 63;
  const int wv = tid >> 6;
  const int wr = wv >> 1;  // o half (0..1)
  const int wc = wv & 1;   // output row within pair (0..1)
  const int oblk = blockIdx.x;
  const int hp = blockIdx.y;
  const int b = blockIdx.z;
  const int l15 = lane & 15, cc = lane >> 4;

  f32x4 acc[4][8] = {};

  // A-frag byte offsets within a kw tile: row = wr*64+m*16+l15, chunk cc
  const int axor = ((cc ^ ((l15 >> 1) & 3)) << 4);
  int aoff[4];
#pragma unroll
  for (int m = 0; m < 4; ++m)
    aoff[m] = 2 * XROWB + (wr * 64 + m * 16 + l15) * 64 + axor;

  const unsigned char* xpb = xp + ((size_t)(b * 8)) * 128 * XROWB;

  for (int i0 = 0; i0 < 8; ++i0) {
    for (int kh = 0; kh < 3; ++kh) {
      // ---- staging: X tasks 0..16 (1040 chunks), W tasks 17..40 (1536)
      for (int task = wv; task < 41; task += 4) {
        if (task < 17) {
          int c = task * 64 + lane;
          if (task < 16 || lane < 16) {
            int q = (c >= 520) ? 1 : 0;
            int wdx = c - q * 520;
            int gr = 2 * hp + kh - 1 + q;
            const unsigned char* src =
                ((unsigned)gr < 128u)
                    ? xpb + ((size_t)(i0 * 128 + gr)) * XROWB + wdx * 16
                    : zrow + wdx * 16;
            glds16(src, lds + task * 1024);  // HW scatters base + lane*16
          }
        } else {
          int t2 = task - 17;
          int c2 = t2 * 64 + lane;
          int kw = c2 >> 9, rest = c2 & 511;
          const unsigned char* src =
              wbf + ((size_t)(((kh * 3 + kw) * 2 + oblk) * 8 + i0)) * WTILEB +
              rest * 16;
          glds16(src, lds + 2 * XROWB + t2 * 1024);
        }
      }
      asm volatile("s_waitcnt vmcnt(0)" ::: "memory");
      __syncthreads();
      // ---- compute
#pragma unroll
      for (int kw = 0; kw < 3; ++kw) {
        bf16x8 a0 = *(const bf16x8*)(lds + kw * WTILEB + aoff[0]);
        bf16x8 a1 = *(const bf16x8*)(lds + kw * WTILEB + aoff[1]);
        bf16x8 a2 = *(const bf16x8*)(lds + kw * WTILEB + aoff[2]);
        bf16x8 a3 = *(const bf16x8*)(lds + kw * WTILEB + aoff[3]);
        __builtin_amdgcn_s_setprio(1);
#pragma unroll
        for (int n = 0; n < 8; ++n) {
          int slot = n * 16 + l15 + kw;
          bf16x8 bn = *(const bf16x8*)(lds + wc * XROWB + slot * 64 +
                                       ((cc ^ ((slot >> 1) & 3)) << 4));
          acc[0][n] = __builtin_amdgcn_mfma_f32_16x16x32_bf16(a0, bn, acc[0][n], 0, 0, 0);
          acc[1][n] = __builtin_amdgcn_mfma_f32_16x16x32_bf16(a1, bn, acc[1][n], 0, 0, 0);
          acc[2][n] = __builtin_amdgcn_mfma_f32_16x16x32_bf16(a2, bn, acc[2][n], 0, 0, 0);
          acc[3][n] = __builtin_amdgcn_mfma_f32_16x16x32_bf16(a3, bn, acc[3][n], 0, 0, 0);
        }
        __builtin_amdgcn_s_setprio(0);
      }
      __syncthreads();
    }
  }

  // ---- epilogue: demod scale + LeakyReLU + coalesced store
  const float* db = dscaled + b * OUT_C + oblk * 128;
  const int r_out = 2 * hp + wc;
  float* ob = out + (((size_t)(b * OUT_C + oblk * 128)) << 14) + r_out * 128;
#pragma unroll
  for (int m = 0; m < 4; ++m) {
#pragma unroll
    for (int r = 0; r < 4; ++r) {
      int oo = wr * 64 + m * 16 + cc * 4 + r;
      float d = db[oo];
#pragma unroll
      for (int n = 0; n < 8; ++n) {
        float v = acc[m][n][r] * d;
        v = (v >= 0.f) ? v : NEG_SLOPE * v;
        ob[((size_t)oo << 14) + n * 16 + l15] = v;
      }
    }
  }
}

// ---- launcher ---------------------------------------------------------------
extern "C" void kernel_launch(void* const* d_in, const int* in_sizes, int n_in,
                              void* d_out, int out_size, void* d_ws,
                              size_t ws_size, hipStream_t stream) {
  const float* x = (const float*)d_in[0];      // [8,256,128,128]
  const float* style = (const float*)d_in[1];  // [8,512]
  const float* weight = (const float*)d_in[2]; // [256,256,3,3]
  const float* mod_w = (const float*)d_in[3];  // [256,512]
  const float* mod_b = (const float*)d_in[4];  // [256]
  float* out = (float*)d_out;                  // [8,256,128,128]

  float* s_ws = (float*)d_ws;                  // 8 KB
  float* dsc = s_ws + 2048;                    // 8 KB
  float* wsq = dsc + 2048;                     // 256 KB
  unsigned char* wbf = (unsigned char*)(wsq + 65536);     // 1.125 MB
  unsigned char* xp = wbf + (size_t)9 * 2 * 8 * WTILEB;   // 65 MB
  unsigned char* zrow = xp + (size_t)8 * 8 * 128 * XROWB; // 8320 B

  style_mod_kernel<<<dim3(8, 4), dim3(256), 0, stream>>>(style, mod_w, mod_b, s_ws);
  wsq_kernel<<<dim3(256), dim3(256), 0, stream>>>(weight, wsq);
  demod_kernel<<<dim3(256), dim3(256), 0, stream>>>(wsq, s_ws, dsc);
  wpack_kernel<<<dim3(9, 2, 8), dim3(256), 0, stream>>>(weight, wbf);
  zfill_kernel<<<dim3(1), dim3(256), 0, stream>>>((float4*)zrow);
  xpack_kernel<<<dim3(16, 8, 8), dim3(256), 0, stream>>>(x, s_ws, xp);

  modconv_kernel<<<dim3(2, 64, 8), dim3(256), 0, stream>>>(xp, wbf, zrow, dsc, out);
}

// Round 8
// 416.910 us; speedup vs baseline: 1.0376x; 1.0376x over previous
//
#include <hip/hip_runtime.h>
#include <hip/hip_bf16.h>
#include <cstddef>
#include <cstdint>

// ModulatedConv2d: B=8, I=O=256, H=W=128, K=3, PAD=1, SD=512.
// y[b,o,p] = leaky( dscaled[b,o] * sum_{kh,kw,i} w[o,i,t] * (x*s)[b,i,p'] )
// R7: "A-direct" conv — weights loaded global->registers (L2-hot), LDS holds
// only the X row (double-buffered, 2-phase pipeline, 1 barrier/phase).
// 5 kernels: style, fused wsq+demod+zfill, wpack (unswizzled), xpack, conv.

#define IN_C 256
#define OUT_C 256
#define HW 16384
#define W_IMG 128
#define SDIM 512
#define SCALE_F 0.020833333333333332f  // 1/48
#define EPS_F 1e-8f
#define NEG_SLOPE 0.2f

#define XROWB 8320   // per (b,iblk,row): 130 slots * 32 i * 2B
#define WTILEB 8192  // per (tap,oblk,iblk): 128 o * 32 i * 2B

typedef short bf16x8 __attribute__((ext_vector_type(8)));
typedef float f32x4 __attribute__((ext_vector_type(4)));

__device__ __forceinline__ unsigned short f2bf(float f) {
  unsigned u = __builtin_bit_cast(unsigned, f);
  unsigned r = u + 0x7FFFu + ((u >> 16) & 1u);
  return (unsigned short)(r >> 16);
}

__device__ __forceinline__ void glds16(const void* g, void* l) {
  __builtin_amdgcn_global_load_lds(
      (const __attribute__((address_space(1))) unsigned int*)g,
      (__attribute__((address_space(3))) unsigned int*)l, 16, 0, 0);
}

// ---- kernel 1: s[b][i] = style[b] . mod_w[i] + mod_b[i] --------------------
__global__ void style_mod_kernel(const float* __restrict__ style,
                                 const float* __restrict__ mod_w,
                                 const float* __restrict__ mod_b,
                                 float* __restrict__ s_out) {
  const int b = blockIdx.x, iq = blockIdx.y;
  const int il = threadIdx.x >> 2, part = threadIdx.x & 3;
  const int i = iq * 64 + il;
  const float4* st4 = (const float4*)(style + (size_t)b * SDIM) + part * 32;
  const float4* mw4 = (const float4*)(mod_w + (size_t)i * SDIM) + part * 32;
  float a = 0.f;
#pragma unroll 8
  for (int j = 0; j < 32; ++j) {
    float4 s = st4[j], w = mw4[j];
    a += s.x * w.x + s.y * w.y + s.z * w.z + s.w * w.w;
  }
  a += __shfl_xor(a, 1);
  a += __shfl_xor(a, 2);
  if (part == 0) s_out[b * IN_C + i] = a + mod_b[i];
}

// ---- kernel 2: fused wsq + demod + zrow fill -------------------------------
// grid 256 (o), 256 thr (i). dscaled[b][o] = SCALE*rsqrt(SCALE^2*T+eps),
// T = sum_i s[b,i]^2 * sum_k w[o,i,k]^2. Block 0 also zeroes zrow.
__global__ void demod_kernel(const float* __restrict__ weight,
                             const float* __restrict__ s_in,
                             float* __restrict__ dscaled,
                             float4* __restrict__ zrow) {
  const int o = blockIdx.x, i = threadIdx.x;
  if (o == 0) {  // zero the guard row (520 x 16B)
    float4 z = {0.f, 0.f, 0.f, 0.f};
    for (int c = i; c < XROWB / 16; c += 256) zrow[c] = z;
  }
  const float* wp = weight + ((size_t)o * IN_C + i) * 9;
  float wq = 0.f;
#pragma unroll
  for (int k = 0; k < 9; ++k) wq += wp[k] * wp[k];
  float vb[8];
#pragma unroll
  for (int b = 0; b < 8; ++b) {
    float sv = s_in[b * IN_C + i];
    vb[b] = sv * sv * wq;
  }
#pragma unroll
  for (int b = 0; b < 8; ++b)
#pragma unroll
    for (int off = 32; off > 0; off >>= 1) vb[b] += __shfl_down(vb[b], off);
  __shared__ float red[4][8];
  const int lane = threadIdx.x & 63, wvid = threadIdx.x >> 6;
  if (lane == 0) {
#pragma unroll
    for (int b = 0; b < 8; ++b) red[wvid][b] = vb[b];
  }
  __syncthreads();
  if (threadIdx.x < 8) {
    float t = red[0][threadIdx.x] + red[1][threadIdx.x] +
              red[2][threadIdx.x] + red[3][threadIdx.x];
    dscaled[threadIdx.x * OUT_C + o] =
        SCALE_F * rsqrtf(SCALE_F * SCALE_F * t + EPS_F);
  }
}

// ---- kernel 3: pack W -> bf16 tiles [tap][oblk2][iblk8][128 o][4 x 16B] ----
// UNSWIZZLED (A is consumed via global->register loads now).
__global__ void wpack_kernel(const float* __restrict__ weight,
                             unsigned char* __restrict__ wbf) {
  int tap = blockIdx.x, oblk = blockIdx.y, iblk = blockIdx.z;
  unsigned char* dst = wbf + ((size_t)((tap * 2 + oblk) * 8 + iblk)) * WTILEB;
  for (int t = threadIdx.x; t < 512; t += 256) {
    int oo = t >> 2, c = t & 3;
    int o = oblk * 128 + oo;
    bf16x8 v;
#pragma unroll
    for (int j = 0; j < 8; ++j) {
      int i = iblk * 32 + c * 8 + j;
      v[j] = (short)f2bf(weight[((size_t)o * IN_C + i) * 9 + tap]);
    }
    *(bf16x8*)(dst + oo * 64 + c * 16) = v;
  }
}

// ---- kernel 4: pack X' = bf16(x*s), [b][iblk][row][130 slots][32 i] --------
// Coalesced float4 reads; LDS transpose (stride-33 pad); swizzled 16B stores
// (B-side still goes through LDS in conv, keeps the XOR swizzle).
__global__ __launch_bounds__(256) void xpack_kernel(
    const float* __restrict__ x, const float* __restrict__ s_in,
    unsigned char* __restrict__ xp) {
  __shared__ short xt[128 * 33];
  const int tid = threadIdx.x;
  const int rb = blockIdx.x, iblk = blockIdx.y, b = blockIdx.z;
  const float* xbase = x + ((size_t)(b * IN_C + iblk * 32)) * HW;
  const int chp = tid >> 5;
  const int lp = tid & 31;
  float sv[4];
#pragma unroll
  for (int p = 0; p < 4; ++p) sv[p] = s_in[b * IN_C + iblk * 32 + p * 8 + chp];

  for (int r = 0; r < 8; ++r) {
    const int row = rb * 8 + r;
#pragma unroll
    for (int p = 0; p < 4; ++p) {
      const int ch = p * 8 + chp;
      float4 v = *(const float4*)(xbase + (size_t)ch * HW + row * W_IMG + lp * 4);
      const int pix0 = lp * 4;
      xt[(pix0 + 0) * 33 + ch] = (short)f2bf(v.x * sv[p]);
      xt[(pix0 + 1) * 33 + ch] = (short)f2bf(v.y * sv[p]);
      xt[(pix0 + 2) * 33 + ch] = (short)f2bf(v.z * sv[p]);
      xt[(pix0 + 3) * 33 + ch] = (short)f2bf(v.w * sv[p]);
    }
    __syncthreads();
    unsigned char* dst = xp + ((size_t)((b * 8 + iblk) * 128 + row)) * XROWB;
    for (int task = tid; task < 520; task += 256) {
      int slot = task >> 2, c = task & 3;
      int cp = c ^ ((slot >> 1) & 3);
      int pix = slot - 1;
      bf16x8 v = (bf16x8)(short)0;
      if ((unsigned)pix < 128u) {
#pragma unroll
        for (int j = 0; j < 8; ++j) v[j] = xt[pix * 33 + c * 8 + j];
      }
      *(bf16x8*)(dst + slot * 64 + cp * 16) = v;
    }
    __syncthreads();
  }
}

// ---- kernel 5: conv GEMM, A-direct, 2-phase pipelined ----------------------
// 1D grid 2048 (XCD-chunked swizzle) -> (oblk 2, h 128, b 8). 256 thr = 4
// waves (2 o-halves x 2 pixel-halves). Wave tile 64o x 64pix (4x4 frags).
// Phase t=(kh,i0): A = 12 global 16B frag loads (L2-hot wbf); X row in LDS,
// double-buffered; stage(t+1) issued before compute(t); 1 barrier/phase.
__global__ __launch_bounds__(256, 2) void modconv_kernel(
    const unsigned char* __restrict__ xp, const unsigned char* __restrict__ wbf,
    const unsigned char* __restrict__ zrow, const float* __restrict__ dscaled,
    float* __restrict__ out) {
  __shared__ __align__(16) unsigned char lds[2 * XROWB];  // 16640 B

  const int tid = threadIdx.x;
  const int lane = tid & 63;
  const int wv = tid >> 6;
  const int wr = wv >> 1;  // o half
  const int wc = wv & 1;   // pixel half
  const int l15 = lane & 15, cc = lane >> 4;

  // XCD-chunked bijective swizzle: 2048 blocks = 8 XCD x 256
  const int bid = blockIdx.x;
  const int logical = (bid & 7) * 256 + (bid >> 3);
  const int oblk = logical & 1;
  const int h = (logical >> 1) & 127;
  const int b = logical >> 8;

  f32x4 acc[4][4] = {};

  const unsigned char* xpb = xp + ((size_t)(b * 8)) * 128 * XROWB;
  const int arow_off = (wr * 64 + l15) * 64 + cc * 16;  // + m*1024

  // ---- prologue: stage phase 0 (kh=0 -> row h-1, i0=0) into buf 0
  {
    const unsigned char* src =
        (h >= 1) ? xpb + ((size_t)(0 * 128 + (h - 1))) * XROWB : zrow;
    for (int task = wv; task < 9; task += 4)
      if (task < 8 || lane < 8)
        glds16(src + task * 1024 + lane * 16, lds + task * 1024);
  }
  asm volatile("s_waitcnt vmcnt(0)" ::: "memory");
  __syncthreads();

  for (int t = 0; t < 24; ++t) {
    const int kh = t >> 3, i0 = t & 7;
    unsigned char* cbuf = lds + (t & 1) * XROWB;

    // ---- A fragment loads (12 x 16B, contiguous 1KB per wave-instr, L2-hot)
    bf16x8 a[3][4];
#pragma unroll
    for (int kw = 0; kw < 3; ++kw) {
      const unsigned char* wt =
          wbf + ((size_t)(((kh * 3 + kw) * 2 + oblk) * 8 + i0)) * WTILEB;
#pragma unroll
      for (int m = 0; m < 4; ++m)
        a[kw][m] = *(const bf16x8*)(wt + m * 1024 + arow_off);
    }

    // ---- stage next phase's X row into the other buffer
    if (t < 23) {
      const int nt = t + 1;
      const int nkh = nt >> 3, ni0 = nt & 7;
      const int gr = h + nkh - 1;
      const unsigned char* src =
          ((unsigned)gr < 128u) ? xpb + ((size_t)(ni0 * 128 + gr)) * XROWB
                                : zrow;
      unsigned char* nbuf = lds + (nt & 1) * XROWB;
      for (int task = wv; task < 9; task += 4)
        if (task < 8 || lane < 8)
          glds16(src + task * 1024 + lane * 16, nbuf + task * 1024);
    }

    // ---- compute: 3 kw x (4 B ds_read_b128 + 16 MFMA)
#pragma unroll
    for (int kw = 0; kw < 3; ++kw) {
      __builtin_amdgcn_s_setprio(1);
#pragma unroll
      for (int n = 0; n < 4; ++n) {
        const int slot = wc * 64 + n * 16 + l15 + kw;
        bf16x8 bn = *(const bf16x8*)(cbuf + slot * 64 +
                                     ((cc ^ ((slot >> 1) & 3)) << 4));
        acc[0][n] = __builtin_amdgcn_mfma_f32_16x16x32_bf16(a[kw][0], bn, acc[0][n], 0, 0, 0);
        acc[1][n] = __builtin_amdgcn_mfma_f32_16x16x32_bf16(a[kw][1], bn, acc[1][n], 0, 0, 0);
        acc[2][n] = __builtin_amdgcn_mfma_f32_16x16x32_bf16(a[kw][2], bn, acc[2][n], 0, 0, 0);
        acc[3][n] = __builtin_amdgcn_mfma_f32_16x16x32_bf16(a[kw][3], bn, acc[3][n], 0, 0, 0);
      }
      __builtin_amdgcn_s_setprio(0);
    }

    // staging was issued a full compute-phase ago -> drain is cheap
    asm volatile("s_waitcnt vmcnt(0)" ::: "memory");
    __syncthreads();
  }

  // ---- epilogue: demod scale + LeakyReLU + coalesced store
  const float* db = dscaled + b * OUT_C + oblk * 128;
  float* ob = out + (((size_t)(b * OUT_C + oblk * 128)) << 14) + h * 128;
#pragma unroll
  for (int m = 0; m < 4; ++m) {
#pragma unroll
    for (int r = 0; r < 4; ++r) {
      int oo = wr * 64 + m * 16 + cc * 4 + r;
      float d = db[oo];
#pragma unroll
      for (int n = 0; n < 4; ++n) {
        float v = acc[m][n][r] * d;
        v = (v >= 0.f) ? v : NEG_SLOPE * v;
        ob[((size_t)oo << 14) + wc * 64 + n * 16 + l15] = v;
      }
    }
  }
}

// ---- launcher ---------------------------------------------------------------
extern "C" void kernel_launch(void* const* d_in, const int* in_sizes, int n_in,
                              void* d_out, int out_size, void* d_ws,
                              size_t ws_size, hipStream_t stream) {
  const float* x = (const float*)d_in[0];      // [8,256,128,128]
  const float* style = (const float*)d_in[1];  // [8,512]
  const float* weight = (const float*)d_in[2]; // [256,256,3,3]
  const float* mod_w = (const float*)d_in[3];  // [256,512]
  const float* mod_b = (const float*)d_in[4];  // [256]
  float* out = (float*)d_out;                  // [8,256,128,128]

  float* s_ws = (float*)d_ws;                  // 8 KB
  float* dsc = s_ws + 2048;                    // 8 KB
  unsigned char* wbf = (unsigned char*)(dsc + 2048);      // 1.125 MB
  unsigned char* xp = wbf + (size_t)9 * 2 * 8 * WTILEB;   // 65 MB
  unsigned char* zrow = xp + (size_t)8 * 8 * 128 * XROWB; // 8320 B

  style_mod_kernel<<<dim3(8, 4), dim3(256), 0, stream>>>(style, mod_w, mod_b, s_ws);
  demod_kernel<<<dim3(256), dim3(256), 0, stream>>>(weight, s_ws, dsc, (float4*)zrow);
  wpack_kernel<<<dim3(9, 2, 8), dim3(256), 0, stream>>>(weight, wbf);
  xpack_kernel<<<dim3(16, 8, 8), dim3(256), 0, stream>>>(x, s_ws, xp);

  modconv_kernel<<<dim3(2048), dim3(256), 0, stream>>>(xp, wbf, zrow, dsc, out);
}